// Round 19
// baseline (430.016 us; speedup 1.0000x reference)
//
#include <hip/hip_runtime.h>

#define NUM_SEG 40000
#define BN_EPS 1e-3f

typedef float f4v __attribute__((ext_vector_type(4)));
typedef _Float16 f16x8 __attribute__((ext_vector_type(8)));
typedef float f32x4 __attribute__((ext_vector_type(4)));

// Order-preserving float->uint encoding (for atomicMax over signed floats).
__device__ __forceinline__ unsigned enc_f(float f) {
    unsigned b = __float_as_uint(f);
    return (b & 0x80000000u) ? ~b : (b | 0x80000000u);
}
__device__ __forceinline__ float dec_f(unsigned u) {
    return __uint_as_float((u & 0x80000000u) ? (u ^ 0x80000000u) : ~u);
}

// ---------------- k_prep: zero segmax + detect int64/int32 + convert unq -> int32 ----------------
__global__ __launch_bounds__(256) void k_prep(const void* __restrict__ unq, int N,
                                              int* __restrict__ unq32,
                                              float4* __restrict__ segz, int nseg4) {
    __shared__ int sflag;
    const int tid = threadIdx.x;
    if (tid < 64) {
        const unsigned int* u = (const unsigned int*)unq;
        int w = ((N / 2) | 1) + 2 * tid;
        unsigned v = (w < N) ? u[w] : 0u;
        unsigned long long b = __ballot(v != 0u);
        if (tid == 0) sflag = (b == 0ull) ? 1 : 0;
    }
    __syncthreads();
    const int flag = sflag;
    const long i = (long)blockIdx.x * 256 + tid;
    if (i < nseg4) segz[i] = make_float4(0.f, 0.f, 0.f, 0.f);   // 0 == enc(-inf)
    if (i < N) unq32[i] = flag ? (int)((const long long*)unq)[i] : ((const int*)unq)[i];
}

// ---------------- k1: f16 2-term MFMA matmul -> raw x to DENSE f16 xtmp, stats, segmax over RAW x ----------------
// LDS 40KB: A_f32[128][256B] chunk-swizzled (c^=(r&15)) at 0; W16_t[64][128B] (c^=(n&7)) at 32768.
// 4 blocks/CU * 4 waves = 16 waves/CU. x = ahi@W16 + alo@W16 (A-split exact; W f16 err ~2^-11).
// segmax from f32 acc (exact); xtmp stored f16 (128B/point) to halve the round-trip bytes.
__global__ __launch_bounds__(256, 4) void k1_mfma(
    const float* __restrict__ in, const float* __restrict__ W,
    const int* __restrict__ unq,
    f16x8* __restrict__ xtmp, float* __restrict__ sums, float* __restrict__ sqs,
    unsigned int* __restrict__ segmax, int N, int NBS) {
    __shared__ __align__(16) char lds[40960];
    // overlay after barrier: xbuf = (float*)lds, [128][68] f32 (34.8KB <= 40KB)
    const int tid = threadIdx.x;
    const int blk = blockIdx.x;
    const long p0 = (long)blk * 128;
    const int wv = tid >> 6;
    const int l  = tid & 63;

    // --- stage W16_t: wave wv covers k in [wv*16, +16); lane l = out-ch n ---
    {
        _Float16 h[16];
        #pragma unroll
        for (int kk = 0; kk < 16; ++kk)
            h[kk] = (_Float16)W[(wv * 16 + kk) * 64 + l];   // coalesced 256B row per kk
        f16x8 c0 = { h[0], h[1], h[2], h[3], h[4], h[5], h[6], h[7] };
        f16x8 c1 = { h[8], h[9], h[10], h[11], h[12], h[13], h[14], h[15] };
        int base = 32768 + l * 128;
        *(f16x8*)(lds + base + (((wv * 2)     ^ (l & 7)) << 4)) = c0;
        *(f16x8*)(lds + base + (((wv * 2 + 1) ^ (l & 7)) << 4)) = c1;
    }
    // --- stage A as raw f32 copy (2048 float4 over 8 iters; swizzled LDS chunk) ---
    #pragma unroll
    for (int it = 0; it < 8; ++it) {
        int f = it * 256 + tid;
        int r = f >> 4, c = f & 15;
        long gp = p0 + r;
        f4v v = {0.f, 0.f, 0.f, 0.f};
        if (gp < N) v = *((const f4v*)in + gp * 16 + c);
        *(f4v*)(lds + r * 256 + ((c ^ (r & 15)) << 4)) = v;
    }
    __syncthreads();

    // --- MFMA: wave wv owns rows [wv*32, +32), all 64 channels ---
    const int lr = l & 15;
    const int lg = l >> 4;
    f32x4 acc[2][4] = {};
    #pragma unroll
    for (int ks = 0; ks < 2; ++ks) {
        f16x8 ah[2], al[2], bh[4];
        #pragma unroll
        for (int mt = 0; mt < 2; ++mt) {
            int r = wv * 32 + mt * 16 + lr;
            int cg = ks * 8 + lg * 2;                       // 16B f32 chunk index
            f4v a0 = *(const f4v*)(lds + r * 256 + (((cg)     ^ (r & 15)) << 4));
            f4v a1 = *(const f4v*)(lds + r * 256 + (((cg + 1) ^ (r & 15)) << 4));
            float av[8] = { a0.x, a0.y, a0.z, a0.w, a1.x, a1.y, a1.z, a1.w };
            #pragma unroll
            for (int j = 0; j < 8; ++j) {
                _Float16 h = (_Float16)av[j];
                ah[mt][j] = h;
                al[mt][j] = (_Float16)(av[j] - (float)h);
            }
        }
        #pragma unroll
        for (int nt = 0; nt < 4; ++nt) {
            int n = nt * 16 + lr;
            int cg = ks * 4 + lg;                           // 16B f16 chunk index
            bh[nt] = *(const f16x8*)(lds + 32768 + n * 128 + ((cg ^ (n & 7)) << 4));
        }
        #pragma unroll
        for (int mt = 0; mt < 2; ++mt)
            #pragma unroll
            for (int nt = 0; nt < 4; ++nt) {
                acc[mt][nt] = __builtin_amdgcn_mfma_f32_16x16x32_f16(ah[mt], bh[nt], acc[mt][nt], 0, 0, 0);
                acc[mt][nt] = __builtin_amdgcn_mfma_f32_16x16x32_f16(al[mt], bh[nt], acc[mt][nt], 0, 0, 0);
            }
    }

    // --- stats: channel c = nt*16 + lr; sum over this wave's 32 points ---
    {
        float s[4], q[4];
        #pragma unroll
        for (int nt = 0; nt < 4; ++nt) {
            s[nt] = 0.f; q[nt] = 0.f;
            #pragma unroll
            for (int mt = 0; mt < 2; ++mt)
                #pragma unroll
                for (int r = 0; r < 4; ++r) {
                    float x = acc[mt][nt][r];
                    s[nt] += x; q[nt] += x * x;
                }
        }
        #pragma unroll
        for (int off = 16; off < 64; off <<= 1) {   // sum lanes sharing lr
            #pragma unroll
            for (int nt = 0; nt < 4; ++nt) {
                s[nt] += __shfl_xor(s[nt], off);
                q[nt] += __shfl_xor(q[nt], off);
            }
        }
        if (l < 16) {
            #pragma unroll
            for (int nt = 0; nt < 4; ++nt) {
                int c = nt * 16 + l;
                sums[(long)c * NBS + blk * 4 + wv] = s[nt];
                sqs [(long)c * NBS + blk * 4 + wv] = q[nt];
            }
        }
    }

    // --- restage raw x into xbuf (overlays staging tiles) ---
    __syncthreads();   // all frag reads done
    float* xbuf = (float*)lds;
    #pragma unroll
    for (int mt = 0; mt < 2; ++mt)
        #pragma unroll
        for (int nt = 0; nt < 4; ++nt)
            #pragma unroll
            for (int r = 0; r < 4; ++r)
                xbuf[(wv * 32 + mt * 16 + lg * 4 + r) * 68 + nt * 16 + lr] = acc[mt][nt][r];
    __syncthreads();

    // --- DENSE store raw x as f16 -> xtmp (128B/point; halves round-trip bytes) ---
    #pragma unroll
    for (int it = 0; it < 4; ++it) {
        int f = it * 256 + tid;
        int p = f >> 3, c = f & 7;
        long gp = p0 + p;
        if (gp < N) {
            const float* src = &xbuf[p * 68 + c * 8];
            f16x8 h;
            #pragma unroll
            for (int j = 0; j < 8; ++j) h[j] = (_Float16)src[j];
            xtmp[gp * 8 + c] = h;
        }
    }

    // --- per-wave run-compressed segmax over raw x: 32 consecutive points, lane = channel ---
    const long gbase = p0 + (long)wv * 32;
    if (gbase < N) {
        const int cnt = (int)min((long)32, (long)N - gbase);
        const int myseg = unq[gbase + ((l < cnt) ? l : (cnt - 1))];
        int cur = __shfl(myseg, 0);
        unsigned runmax = 0u;
        for (int r = 0; r < cnt; ++r) {
            int seg = __shfl(myseg, r);
            if (seg != cur) {
                atomicMax(&segmax[(long)cur * 64 + l], runmax);
                cur = seg; runmax = 0u;
            }
            runmax = max(runmax, enc_f(xbuf[(wv * 32 + r) * 68 + l]));
        }
        atomicMax(&segmax[(long)cur * 64 + l], runmax);
    }
}

// ---------------- k2: reduce partials -> scale/shift per channel ----------------
__global__ __launch_bounds__(256) void k2_stats(
    const float* __restrict__ sums, const float* __restrict__ sqs,
    const float* __restrict__ gamma, const float* __restrict__ beta,
    float* __restrict__ ss, int N, int NBS) {
    int c = blockIdx.x;
    int tid = threadIdx.x;
    float s = 0.f, q = 0.f;
    for (int i = tid; i < NBS; i += 256) { s += sums[(long)c * NBS + i]; q += sqs[(long)c * NBS + i]; }
    __shared__ float ls[256], lq[256];
    ls[tid] = s; lq[tid] = q;
    __syncthreads();
    for (int off = 128; off > 0; off >>= 1) {
        if (tid < off) { ls[tid] += ls[tid + off]; lq[tid] += lq[tid + off]; }
        __syncthreads();
    }
    if (tid == 0) {
        float mean = ls[0] / (float)N;
        float var  = lq[0] / (float)N - mean * mean;   // biased, matches jnp.var
        float sc = gamma[c] * rsqrtf(var + BN_EPS);
        float sh = beta[c] - mean * sc;
        ss[c] = sc; ss[64 + c] = sh;
    }
}

// ---------------- k4: 16 thr/point: sub<8 unpack f16 x -> left half; sub>=8 gather segmax -> right ----------------
__global__ __launch_bounds__(256) void k4_final(
    float* __restrict__ out, const int* __restrict__ unq,
    const f16x8* __restrict__ xtmp,
    const unsigned int* __restrict__ segmax, const float* __restrict__ ss, int N) {
    long t = (long)blockIdx.x * 256 + threadIdx.x;
    long p = t >> 4;
    int sub = (int)(t & 15);
    if (p >= N) return;
    const float4* ss4 = (const float4*)ss;

    if (sub < 8) {
        // left: channels sub*8 .. +7
        float4 scA = ss4[sub * 2], scB = ss4[sub * 2 + 1];
        float4 shA = ss4[16 + sub * 2], shB = ss4[16 + sub * 2 + 1];
        f16x8 h = xtmp[p * 8 + sub];
        f4v a, b;
        a.x = fmaxf(fmaf((float)h[0], scA.x, shA.x), 0.f);
        a.y = fmaxf(fmaf((float)h[1], scA.y, shA.y), 0.f);
        a.z = fmaxf(fmaf((float)h[2], scA.z, shA.z), 0.f);
        a.w = fmaxf(fmaf((float)h[3], scA.w, shA.w), 0.f);
        b.x = fmaxf(fmaf((float)h[4], scB.x, shB.x), 0.f);
        b.y = fmaxf(fmaf((float)h[5], scB.y, shB.y), 0.f);
        b.z = fmaxf(fmaf((float)h[6], scB.z, shB.z), 0.f);
        b.w = fmaxf(fmaf((float)h[7], scB.w, shB.w), 0.f);
        __builtin_nontemporal_store(a, (f4v*)out + p * 32 + sub * 2);
        __builtin_nontemporal_store(b, (f4v*)out + p * 32 + sub * 2 + 1);
    } else {
        // right: channels s8*8 .. +7 from segmax (exact f32 raw-x max, monotone-mapped)
        int s8 = sub - 8;
        float4 scA = ss4[s8 * 2], scB = ss4[s8 * 2 + 1];
        float4 shA = ss4[16 + s8 * 2], shB = ss4[16 + s8 * 2 + 1];
        int seg = unq[p];
        uint4 m0 = ((const uint4*)segmax)[(long)seg * 16 + s8 * 2];
        uint4 m1 = ((const uint4*)segmax)[(long)seg * 16 + s8 * 2 + 1];
        f4v a, b;
        a.x = fmaxf(fmaf(dec_f(m0.x), scA.x, shA.x), 0.f);
        a.y = fmaxf(fmaf(dec_f(m0.y), scA.y, shA.y), 0.f);
        a.z = fmaxf(fmaf(dec_f(m0.z), scA.z, shA.z), 0.f);
        a.w = fmaxf(fmaf(dec_f(m0.w), scA.w, shA.w), 0.f);
        b.x = fmaxf(fmaf(dec_f(m1.x), scB.x, shB.x), 0.f);
        b.y = fmaxf(fmaf(dec_f(m1.y), scB.y, shB.y), 0.f);
        b.z = fmaxf(fmaf(dec_f(m1.z), scB.z, shB.z), 0.f);
        b.w = fmaxf(fmaf(dec_f(m1.w), scB.w, shB.w), 0.f);
        __builtin_nontemporal_store(a, (f4v*)out + p * 32 + 16 + s8 * 2);
        __builtin_nontemporal_store(b, (f4v*)out + p * 32 + 16 + s8 * 2 + 1);
    }
}

extern "C" void kernel_launch(void* const* d_in, const int* in_sizes, int n_in,
                              void* d_out, int out_size, void* d_ws, size_t ws_size,
                              hipStream_t stream) {
    const float* in    = (const float*)d_in[0];
    const float* W     = (const float*)d_in[1];
    const float* gamma = (const float*)d_in[2];
    const float* beta  = (const float*)d_in[3];
    const void*  unq   = d_in[4];
    float* out = (float*)d_out;

    const int N   = in_sizes[0] / 64;
    const int NB  = (N + 127) / 128;
    const int NBS = 4 * NB;

    char* ws = (char*)d_ws;
    unsigned int* segmax = (unsigned int*)ws;                    // 10.24 MB (encoded floats)
    size_t off = (size_t)NUM_SEG * 64 * 4;
    float* sums = (float*)(ws + off); off += (size_t)64 * NBS * 4;
    float* sqs  = (float*)(ws + off); off += (size_t)64 * NBS * 4;
    float* ss   = (float*)(ws + off); off += 512;
    int*   unq32= (int*)(ws + off);   off += (size_t)N * 4;
    off = (off + 255) & ~(size_t)255;
    f16x8* xtmp = (f16x8*)(ws + off); off += (size_t)N * 64 * 2; // 128 MB dense f16 raw-x

    const int n4 = NUM_SEG * 64 / 4;
    const int gprep = max((N + 255) / 256, (n4 + 255) / 256);
    k_prep<<<gprep, 256, 0, stream>>>(unq, N, unq32, (float4*)segmax, n4);
    k1_mfma<<<NB, 256, 0, stream>>>(in, W, unq32, xtmp, sums, sqs, segmax, N, NBS);
    k2_stats<<<64, 256, 0, stream>>>(sums, sqs, gamma, beta, ss, N, NBS);
    k4_final<<<(int)(((long)N * 16 + 255) / 256), 256, 0, stream>>>(out, unq32, xtmp, segmax, ss, N);
}

// Round 20
// 280.457 us; speedup vs baseline: 1.5333x; 1.5333x over previous
//
#include <hip/hip_runtime.h>

#define NUM_SEG 40000
#define BN_EPS 1e-3f

typedef float f4v __attribute__((ext_vector_type(4)));
typedef _Float16 f16x8 __attribute__((ext_vector_type(8)));
typedef _Float16 f16x4v __attribute__((ext_vector_type(4)));
typedef float f32x4 __attribute__((ext_vector_type(4)));

// Order-preserving float->uint encoding (for atomicMax over signed floats).
__device__ __forceinline__ unsigned enc_f(float f) {
    unsigned b = __float_as_uint(f);
    return (b & 0x80000000u) ? ~b : (b | 0x80000000u);
}
__device__ __forceinline__ float dec_f(unsigned u) {
    return __uint_as_float((u & 0x80000000u) ? (u ^ 0x80000000u) : ~u);
}

// ---------------- k_prep: zero segmax + detect int64/int32 + convert unq -> int32 ----------------
__global__ __launch_bounds__(256) void k_prep(const void* __restrict__ unq, int N,
                                              int* __restrict__ unq32,
                                              float4* __restrict__ segz, int nseg4) {
    __shared__ int sflag;
    const int tid = threadIdx.x;
    if (tid < 64) {
        const unsigned int* u = (const unsigned int*)unq;
        int w = ((N / 2) | 1) + 2 * tid;
        unsigned v = (w < N) ? u[w] : 0u;
        unsigned long long b = __ballot(v != 0u);
        if (tid == 0) sflag = (b == 0ull) ? 1 : 0;
    }
    __syncthreads();
    const int flag = sflag;
    const long i = (long)blockIdx.x * 256 + tid;
    if (i < nseg4) segz[i] = make_float4(0.f, 0.f, 0.f, 0.f);   // 0 == enc(-inf)
    if (i < N) unq32[i] = flag ? (int)((const long long*)unq)[i] : ((const int*)unq)[i];
}

// ---------------- k1: f16 2-term MFMA matmul -> raw x to DENSE f16 xtmp, stats, segmax over RAW x ----------------
// LDS 40KB: A_f32[128][256B] chunk-swizzled (c^=(r&15)) at 0; W16_t[64][128B] (c^=(n&7)) at 32768.
// 4 blocks/CU * 4 waves = 16 waves/CU. x = ahi@W16 + alo@W16 (A-split exact; W f16 err ~2^-11).
// segmax from f32 acc (exact); xtmp stored f16 (128B/point) to halve the round-trip bytes.
__global__ __launch_bounds__(256, 4) void k1_mfma(
    const float* __restrict__ in, const float* __restrict__ W,
    const int* __restrict__ unq,
    f16x8* __restrict__ xtmp, float* __restrict__ sums, float* __restrict__ sqs,
    unsigned int* __restrict__ segmax, int N, int NBS) {
    __shared__ __align__(16) char lds[40960];
    // overlay after barrier: xbuf = (float*)lds, [128][68] f32 (34.8KB <= 40KB)
    const int tid = threadIdx.x;
    const int blk = blockIdx.x;
    const long p0 = (long)blk * 128;
    const int wv = tid >> 6;
    const int l  = tid & 63;

    // --- stage W16_t: wave wv covers k in [wv*16, +16); lane l = out-ch n ---
    {
        _Float16 h[16];
        #pragma unroll
        for (int kk = 0; kk < 16; ++kk)
            h[kk] = (_Float16)W[(wv * 16 + kk) * 64 + l];   // coalesced 256B row per kk
        f16x8 c0 = { h[0], h[1], h[2], h[3], h[4], h[5], h[6], h[7] };
        f16x8 c1 = { h[8], h[9], h[10], h[11], h[12], h[13], h[14], h[15] };
        int base = 32768 + l * 128;
        *(f16x8*)(lds + base + (((wv * 2)     ^ (l & 7)) << 4)) = c0;
        *(f16x8*)(lds + base + (((wv * 2 + 1) ^ (l & 7)) << 4)) = c1;
    }
    // --- stage A as raw f32 copy (2048 float4 over 8 iters; swizzled LDS chunk) ---
    #pragma unroll
    for (int it = 0; it < 8; ++it) {
        int f = it * 256 + tid;
        int r = f >> 4, c = f & 15;
        long gp = p0 + r;
        f4v v = {0.f, 0.f, 0.f, 0.f};
        if (gp < N) v = *((const f4v*)in + gp * 16 + c);
        *(f4v*)(lds + r * 256 + ((c ^ (r & 15)) << 4)) = v;
    }
    __syncthreads();

    // --- MFMA: wave wv owns rows [wv*32, +32), all 64 channels ---
    const int lr = l & 15;
    const int lg = l >> 4;
    f32x4 acc[2][4] = {};
    #pragma unroll
    for (int ks = 0; ks < 2; ++ks) {
        f16x8 ah[2], al[2], bh[4];
        #pragma unroll
        for (int mt = 0; mt < 2; ++mt) {
            int r = wv * 32 + mt * 16 + lr;
            int cg = ks * 8 + lg * 2;                       // 16B f32 chunk index
            f4v a0 = *(const f4v*)(lds + r * 256 + (((cg)     ^ (r & 15)) << 4));
            f4v a1 = *(const f4v*)(lds + r * 256 + (((cg + 1) ^ (r & 15)) << 4));
            float av[8] = { a0.x, a0.y, a0.z, a0.w, a1.x, a1.y, a1.z, a1.w };
            #pragma unroll
            for (int j = 0; j < 8; ++j) {
                _Float16 h = (_Float16)av[j];
                ah[mt][j] = h;
                al[mt][j] = (_Float16)(av[j] - (float)h);
            }
        }
        #pragma unroll
        for (int nt = 0; nt < 4; ++nt) {
            int n = nt * 16 + lr;
            int cg = ks * 4 + lg;                           // 16B f16 chunk index
            bh[nt] = *(const f16x8*)(lds + 32768 + n * 128 + ((cg ^ (n & 7)) << 4));
        }
        #pragma unroll
        for (int mt = 0; mt < 2; ++mt)
            #pragma unroll
            for (int nt = 0; nt < 4; ++nt) {
                acc[mt][nt] = __builtin_amdgcn_mfma_f32_16x16x32_f16(ah[mt], bh[nt], acc[mt][nt], 0, 0, 0);
                acc[mt][nt] = __builtin_amdgcn_mfma_f32_16x16x32_f16(al[mt], bh[nt], acc[mt][nt], 0, 0, 0);
            }
    }

    // --- stats: channel c = nt*16 + lr; sum over this wave's 32 points ---
    {
        float s[4], q[4];
        #pragma unroll
        for (int nt = 0; nt < 4; ++nt) {
            s[nt] = 0.f; q[nt] = 0.f;
            #pragma unroll
            for (int mt = 0; mt < 2; ++mt)
                #pragma unroll
                for (int r = 0; r < 4; ++r) {
                    float x = acc[mt][nt][r];
                    s[nt] += x; q[nt] += x * x;
                }
        }
        #pragma unroll
        for (int off = 16; off < 64; off <<= 1) {   // sum lanes sharing lr
            #pragma unroll
            for (int nt = 0; nt < 4; ++nt) {
                s[nt] += __shfl_xor(s[nt], off);
                q[nt] += __shfl_xor(q[nt], off);
            }
        }
        if (l < 16) {
            #pragma unroll
            for (int nt = 0; nt < 4; ++nt) {
                int c = nt * 16 + l;
                sums[(long)c * NBS + blk * 4 + wv] = s[nt];
                sqs [(long)c * NBS + blk * 4 + wv] = q[nt];
            }
        }
    }

    // --- restage raw x into xbuf (overlays staging tiles) ---
    __syncthreads();   // all frag reads done
    float* xbuf = (float*)lds;
    #pragma unroll
    for (int mt = 0; mt < 2; ++mt)
        #pragma unroll
        for (int nt = 0; nt < 4; ++nt)
            #pragma unroll
            for (int r = 0; r < 4; ++r)
                xbuf[(wv * 32 + mt * 16 + lg * 4 + r) * 68 + nt * 16 + lr] = acc[mt][nt][r];
    __syncthreads();

    // --- DENSE store raw x as f16 -> xtmp (128B/point; 1KB contiguous per wave) ---
    #pragma unroll
    for (int it = 0; it < 4; ++it) {
        int f = it * 256 + tid;
        int p = f >> 3, c = f & 7;
        long gp = p0 + p;
        if (gp < N) {
            const float* src = &xbuf[p * 68 + c * 8];
            f16x8 h;
            #pragma unroll
            for (int j = 0; j < 8; ++j) h[j] = (_Float16)src[j];
            xtmp[gp * 8 + c] = h;
        }
    }

    // --- per-wave run-compressed segmax over raw x: 32 consecutive points, lane = channel ---
    const long gbase = p0 + (long)wv * 32;
    if (gbase < N) {
        const int cnt = (int)min((long)32, (long)N - gbase);
        const int myseg = unq[gbase + ((l < cnt) ? l : (cnt - 1))];
        int cur = __shfl(myseg, 0);
        unsigned runmax = 0u;
        for (int r = 0; r < cnt; ++r) {
            int seg = __shfl(myseg, r);
            if (seg != cur) {
                atomicMax(&segmax[(long)cur * 64 + l], runmax);
                cur = seg; runmax = 0u;
            }
            runmax = max(runmax, enc_f(xbuf[(wv * 32 + r) * 68 + l]));
        }
        atomicMax(&segmax[(long)cur * 64 + l], runmax);
    }
}

// ---------------- k2: reduce partials -> scale/shift per channel ----------------
__global__ __launch_bounds__(256) void k2_stats(
    const float* __restrict__ sums, const float* __restrict__ sqs,
    const float* __restrict__ gamma, const float* __restrict__ beta,
    float* __restrict__ ss, int N, int NBS) {
    int c = blockIdx.x;
    int tid = threadIdx.x;
    float s = 0.f, q = 0.f;
    for (int i = tid; i < NBS; i += 256) { s += sums[(long)c * NBS + i]; q += sqs[(long)c * NBS + i]; }
    __shared__ float ls[256], lq[256];
    ls[tid] = s; lq[tid] = q;
    __syncthreads();
    for (int off = 128; off > 0; off >>= 1) {
        if (tid < off) { ls[tid] += ls[tid + off]; lq[tid] += lq[tid + off]; }
        __syncthreads();
    }
    if (tid == 0) {
        float mean = ls[0] / (float)N;
        float var  = lq[0] / (float)N - mean * mean;   // biased, matches jnp.var
        float sc = gamma[c] * rsqrtf(var + BN_EPS);
        float sh = beta[c] - mean * sc;
        ss[c] = sc; ss[64 + c] = sh;
    }
}

// ---------------- k4: R18 mapping (16 thr/point, qq owns left-f4 qq AND right-f4 qq); f16x4 left loads ----------------
__global__ __launch_bounds__(256) void k4_final(
    float* __restrict__ out, const int* __restrict__ unq,
    const f16x4v* __restrict__ xtmp,
    const unsigned int* __restrict__ segmax, const float* __restrict__ ss, int N) {
    long t = (long)blockIdx.x * 256 + threadIdx.x;
    long p = t >> 4;
    int qq = (int)(t & 15);
    if (p >= N) return;
    const float4* ss4 = (const float4*)ss;
    float4 sc4 = ss4[qq], sh4 = ss4[16 + qq];

    // left: y = relu(sc*x + sh); x from f16 xtmp (8B/lane, 128B contiguous per point)
    f16x4v h = xtmp[p * 16 + qq];
    f4v y4;
    y4.x = fmaxf(fmaf((float)h[0], sc4.x, sh4.x), 0.f);
    y4.y = fmaxf(fmaf((float)h[1], sc4.y, sh4.y), 0.f);
    y4.z = fmaxf(fmaf((float)h[2], sc4.z, sh4.z), 0.f);
    y4.w = fmaxf(fmaf((float)h[3], sc4.w, sh4.w), 0.f);
    __builtin_nontemporal_store(y4, (f4v*)out + p * 32 + qq);      // dense 256B per 16-lane group

    // right: decode segmax(raw f32 x), same monotone map (exact for the argmax point up to f16-W matmul err)
    int seg = unq[p];
    uint4 m4 = ((const uint4*)segmax)[(long)seg * 16 + qq];
    f4v z4;
    z4.x = fmaxf(fmaf(dec_f(m4.x), sc4.x, sh4.x), 0.f);
    z4.y = fmaxf(fmaf(dec_f(m4.y), sc4.y, sh4.y), 0.f);
    z4.z = fmaxf(fmaf(dec_f(m4.z), sc4.z, sh4.z), 0.f);
    z4.w = fmaxf(fmaf(dec_f(m4.w), sc4.w, sh4.w), 0.f);
    __builtin_nontemporal_store(z4, (f4v*)out + p * 32 + 16 + qq); // dense 256B per 16-lane group
}

extern "C" void kernel_launch(void* const* d_in, const int* in_sizes, int n_in,
                              void* d_out, int out_size, void* d_ws, size_t ws_size,
                              hipStream_t stream) {
    const float* in    = (const float*)d_in[0];
    const float* W     = (const float*)d_in[1];
    const float* gamma = (const float*)d_in[2];
    const float* beta  = (const float*)d_in[3];
    const void*  unq   = d_in[4];
    float* out = (float*)d_out;

    const int N   = in_sizes[0] / 64;
    const int NB  = (N + 127) / 128;
    const int NBS = 4 * NB;

    char* ws = (char*)d_ws;
    unsigned int* segmax = (unsigned int*)ws;                    // 10.24 MB (encoded floats)
    size_t off = (size_t)NUM_SEG * 64 * 4;
    float* sums = (float*)(ws + off); off += (size_t)64 * NBS * 4;
    float* sqs  = (float*)(ws + off); off += (size_t)64 * NBS * 4;
    float* ss   = (float*)(ws + off); off += 512;
    int*   unq32= (int*)(ws + off);   off += (size_t)N * 4;
    off = (off + 255) & ~(size_t)255;
    f16x8* xtmp = (f16x8*)(ws + off); off += (size_t)N * 64 * 2; // 128 MB dense f16 raw-x

    const int n4 = NUM_SEG * 64 / 4;
    const int gprep = max((N + 255) / 256, (n4 + 255) / 256);
    k_prep<<<gprep, 256, 0, stream>>>(unq, N, unq32, (float4*)segmax, n4);
    k1_mfma<<<NB, 256, 0, stream>>>(in, W, unq32, xtmp, sums, sqs, segmax, N, NBS);
    k2_stats<<<64, 256, 0, stream>>>(sums, sqs, gamma, beta, ss, N, NBS);
    k4_final<<<(int)(((long)N * 16 + 255) / 256), 256, 0, stream>>>(out, unq32, (const f16x4v*)xtmp, segmax, ss, N);
}

// Round 21
// 254.772 us; speedup vs baseline: 1.6878x; 1.1008x over previous
//
#include <hip/hip_runtime.h>

#define NUM_SEG 40000
#define BN_EPS 1e-3f

typedef float f4v __attribute__((ext_vector_type(4)));
typedef _Float16 f16x8 __attribute__((ext_vector_type(8)));
typedef _Float16 f16x4v __attribute__((ext_vector_type(4)));
typedef float f32x4 __attribute__((ext_vector_type(4)));

// Order-preserving float->uint encoding (for atomicMax over signed floats).
__device__ __forceinline__ unsigned enc_f(float f) {
    unsigned b = __float_as_uint(f);
    return (b & 0x80000000u) ? ~b : (b | 0x80000000u);
}
__device__ __forceinline__ float dec_f(unsigned u) {
    return __uint_as_float((u & 0x80000000u) ? (u ^ 0x80000000u) : ~u);
}

// Direct global->LDS DMA, 16B per lane. LDS dest is WAVE-UNIFORM base (HW adds lane*16);
// global src is per-lane (pre-swizzled to realize the LDS swizzle — m173 pattern).
__device__ __forceinline__ void gload_lds16(const void* g, void* l) {
    __builtin_amdgcn_global_load_lds(
        (const __attribute__((address_space(1))) unsigned int*)g,
        (__attribute__((address_space(3))) unsigned int*)l, 16, 0, 0);
}

// ---------------- k_prep: zero segmax + detect int64/int32 + convert unq -> int32 ----------------
__global__ __launch_bounds__(256) void k_prep(const void* __restrict__ unq, int N,
                                              int* __restrict__ unq32,
                                              float4* __restrict__ segz, int nseg4) {
    __shared__ int sflag;
    const int tid = threadIdx.x;
    if (tid < 64) {
        const unsigned int* u = (const unsigned int*)unq;
        int w = ((N / 2) | 1) + 2 * tid;
        unsigned v = (w < N) ? u[w] : 0u;
        unsigned long long b = __ballot(v != 0u);
        if (tid == 0) sflag = (b == 0ull) ? 1 : 0;
    }
    __syncthreads();
    const int flag = sflag;
    const long i = (long)blockIdx.x * 256 + tid;
    if (i < nseg4) segz[i] = make_float4(0.f, 0.f, 0.f, 0.f);   // 0 == enc(-inf)
    if (i < N) unq32[i] = flag ? (int)((const long long*)unq)[i] : ((const int*)unq)[i];
}

// ---------------- k1: f16 2-term MFMA matmul -> raw x to DENSE f16 xtmp, stats, segmax over RAW x ----------------
// LDS 40KB: A_f32[128][256B] chunk-swizzled (c^=(r&15)) at 0; W16_t[64][128B] (c^=(n&7)) at 32768.
// 4 blocks/CU * 4 waves = 16 waves/CU. x = ahi@W16 + alo@W16 (A-split exact; W f16 err ~2^-11).
// A staged via global_load_lds (no VGPR round trip); swizzle realized by pre-swizzled global src.
__global__ __launch_bounds__(256, 4) void k1_mfma(
    const float* __restrict__ in, const float* __restrict__ W,
    const int* __restrict__ unq,
    f16x8* __restrict__ xtmp, float* __restrict__ sums, float* __restrict__ sqs,
    unsigned int* __restrict__ segmax, int N, int NBS) {
    __shared__ __align__(16) char lds[40960];
    // overlay after barrier: xbuf = (float*)lds, [128][68] f32 (34.8KB <= 40KB)
    const int tid = threadIdx.x;
    const int blk = blockIdx.x;
    const long p0 = (long)blk * 128;
    const int wv = tid >> 6;
    const int l  = tid & 63;

    // --- stage W16_t: wave wv covers k in [wv*16, +16); lane l = out-ch n ---
    {
        _Float16 h[16];
        #pragma unroll
        for (int kk = 0; kk < 16; ++kk)
            h[kk] = (_Float16)W[(wv * 16 + kk) * 64 + l];   // coalesced 256B row per kk
        f16x8 c0 = { h[0], h[1], h[2], h[3], h[4], h[5], h[6], h[7] };
        f16x8 c1 = { h[8], h[9], h[10], h[11], h[12], h[13], h[14], h[15] };
        int base = 32768 + l * 128;
        *(f16x8*)(lds + base + (((wv * 2)     ^ (l & 7)) << 4)) = c0;
        *(f16x8*)(lds + base + (((wv * 2 + 1) ^ (l & 7)) << 4)) = c1;
    }
    // --- stage A: 2048 16B chunks; fast path = direct global->LDS DMA, pre-swizzled source ---
    if (p0 + 128 <= (long)N) {
        #pragma unroll
        for (int it = 0; it < 8; ++it) {
            int w = it * 4 + wv;                 // 1KB window index (wave-uniform)
            int q = w * 64 + l;                  // chunk this lane fetches
            int r = q >> 4, c = q & 15;
            gload_lds16((const f4v*)in + (p0 + r) * 16 + (c ^ (r & 15)),
                        lds + w * 1024);
        }
    } else {
        #pragma unroll
        for (int it = 0; it < 8; ++it) {         // tail block: guarded VGPR path
            int f = it * 256 + tid;
            int r = f >> 4, c = f & 15;
            long gp = p0 + r;
            f4v v = {0.f, 0.f, 0.f, 0.f};
            if (gp < N) v = *((const f4v*)in + gp * 16 + c);
            *(f4v*)(lds + r * 256 + ((c ^ (r & 15)) << 4)) = v;
        }
    }
    __syncthreads();

    // --- MFMA: wave wv owns rows [wv*32, +32), all 64 channels ---
    const int lr = l & 15;
    const int lg = l >> 4;
    f32x4 acc[2][4] = {};
    #pragma unroll
    for (int ks = 0; ks < 2; ++ks) {
        f16x8 ah[2], al[2], bh[4];
        #pragma unroll
        for (int mt = 0; mt < 2; ++mt) {
            int r = wv * 32 + mt * 16 + lr;
            int cg = ks * 8 + lg * 2;                       // 16B f32 chunk index
            f4v a0 = *(const f4v*)(lds + r * 256 + (((cg)     ^ (r & 15)) << 4));
            f4v a1 = *(const f4v*)(lds + r * 256 + (((cg + 1) ^ (r & 15)) << 4));
            float av[8] = { a0.x, a0.y, a0.z, a0.w, a1.x, a1.y, a1.z, a1.w };
            #pragma unroll
            for (int j = 0; j < 8; ++j) {
                _Float16 h = (_Float16)av[j];
                ah[mt][j] = h;
                al[mt][j] = (_Float16)(av[j] - (float)h);
            }
        }
        #pragma unroll
        for (int nt = 0; nt < 4; ++nt) {
            int n = nt * 16 + lr;
            int cg = ks * 4 + lg;                           // 16B f16 chunk index
            bh[nt] = *(const f16x8*)(lds + 32768 + n * 128 + ((cg ^ (n & 7)) << 4));
        }
        #pragma unroll
        for (int mt = 0; mt < 2; ++mt)
            #pragma unroll
            for (int nt = 0; nt < 4; ++nt) {
                acc[mt][nt] = __builtin_amdgcn_mfma_f32_16x16x32_f16(ah[mt], bh[nt], acc[mt][nt], 0, 0, 0);
                acc[mt][nt] = __builtin_amdgcn_mfma_f32_16x16x32_f16(al[mt], bh[nt], acc[mt][nt], 0, 0, 0);
            }
    }

    // --- stats: channel c = nt*16 + lr; sum over this wave's 32 points ---
    {
        float s[4], q[4];
        #pragma unroll
        for (int nt = 0; nt < 4; ++nt) {
            s[nt] = 0.f; q[nt] = 0.f;
            #pragma unroll
            for (int mt = 0; mt < 2; ++mt)
                #pragma unroll
                for (int r = 0; r < 4; ++r) {
                    float x = acc[mt][nt][r];
                    s[nt] += x; q[nt] += x * x;
                }
        }
        #pragma unroll
        for (int off = 16; off < 64; off <<= 1) {   // sum lanes sharing lr
            #pragma unroll
            for (int nt = 0; nt < 4; ++nt) {
                s[nt] += __shfl_xor(s[nt], off);
                q[nt] += __shfl_xor(q[nt], off);
            }
        }
        if (l < 16) {
            #pragma unroll
            for (int nt = 0; nt < 4; ++nt) {
                int c = nt * 16 + l;
                sums[(long)c * NBS + blk * 4 + wv] = s[nt];
                sqs [(long)c * NBS + blk * 4 + wv] = q[nt];
            }
        }
    }

    // --- restage raw x into xbuf (overlays staging tiles) ---
    __syncthreads();   // all frag reads done
    float* xbuf = (float*)lds;
    #pragma unroll
    for (int mt = 0; mt < 2; ++mt)
        #pragma unroll
        for (int nt = 0; nt < 4; ++nt)
            #pragma unroll
            for (int r = 0; r < 4; ++r)
                xbuf[(wv * 32 + mt * 16 + lg * 4 + r) * 68 + nt * 16 + lr] = acc[mt][nt][r];
    __syncthreads();

    // --- DENSE store raw x as f16 -> xtmp (128B/point; 1KB contiguous per wave) ---
    #pragma unroll
    for (int it = 0; it < 4; ++it) {
        int f = it * 256 + tid;
        int p = f >> 3, c = f & 7;
        long gp = p0 + p;
        if (gp < N) {
            const float* src = &xbuf[p * 68 + c * 8];
            f16x8 h;
            #pragma unroll
            for (int j = 0; j < 8; ++j) h[j] = (_Float16)src[j];
            xtmp[gp * 8 + c] = h;
        }
    }

    // --- per-wave run-compressed segmax over raw x: 32 consecutive points, lane = channel ---
    const long gbase = p0 + (long)wv * 32;
    if (gbase < N) {
        const int cnt = (int)min((long)32, (long)N - gbase);
        const int myseg = unq[gbase + ((l < cnt) ? l : (cnt - 1))];
        int cur = __shfl(myseg, 0);
        unsigned runmax = 0u;
        for (int r = 0; r < cnt; ++r) {
            int seg = __shfl(myseg, r);
            if (seg != cur) {
                atomicMax(&segmax[(long)cur * 64 + l], runmax);
                cur = seg; runmax = 0u;
            }
            runmax = max(runmax, enc_f(xbuf[(wv * 32 + r) * 68 + l]));
        }
        atomicMax(&segmax[(long)cur * 64 + l], runmax);
    }
}

// ---------------- k2: reduce partials -> scale/shift per channel ----------------
__global__ __launch_bounds__(256) void k2_stats(
    const float* __restrict__ sums, const float* __restrict__ sqs,
    const float* __restrict__ gamma, const float* __restrict__ beta,
    float* __restrict__ ss, int N, int NBS) {
    int c = blockIdx.x;
    int tid = threadIdx.x;
    float s = 0.f, q = 0.f;
    for (int i = tid; i < NBS; i += 256) { s += sums[(long)c * NBS + i]; q += sqs[(long)c * NBS + i]; }
    __shared__ float ls[256], lq[256];
    ls[tid] = s; lq[tid] = q;
    __syncthreads();
    for (int off = 128; off > 0; off >>= 1) {
        if (tid < off) { ls[tid] += ls[tid + off]; lq[tid] += lq[tid + off]; }
        __syncthreads();
    }
    if (tid == 0) {
        float mean = ls[0] / (float)N;
        float var  = lq[0] / (float)N - mean * mean;   // biased, matches jnp.var
        float sc = gamma[c] * rsqrtf(var + BN_EPS);
        float sh = beta[c] - mean * sc;
        ss[c] = sc; ss[64 + c] = sh;
    }
}

// ---------------- k4: 16 thr/point, qq owns left-f4 qq AND right-f4 qq (dense 256B runs) ----------------
__global__ __launch_bounds__(256) void k4_final(
    float* __restrict__ out, const int* __restrict__ unq,
    const f16x4v* __restrict__ xtmp,
    const unsigned int* __restrict__ segmax, const float* __restrict__ ss, int N) {
    long t = (long)blockIdx.x * 256 + threadIdx.x;
    long p = t >> 4;
    int qq = (int)(t & 15);
    if (p >= N) return;
    const float4* ss4 = (const float4*)ss;
    float4 sc4 = ss4[qq], sh4 = ss4[16 + qq];

    // left: y = relu(sc*x + sh); x from f16 xtmp (8B/lane, 128B contiguous per point)
    f16x4v h = xtmp[p * 16 + qq];
    f4v y4;
    y4.x = fmaxf(fmaf((float)h[0], sc4.x, sh4.x), 0.f);
    y4.y = fmaxf(fmaf((float)h[1], sc4.y, sh4.y), 0.f);
    y4.z = fmaxf(fmaf((float)h[2], sc4.z, sh4.z), 0.f);
    y4.w = fmaxf(fmaf((float)h[3], sc4.w, sh4.w), 0.f);
    __builtin_nontemporal_store(y4, (f4v*)out + p * 32 + qq);      // dense 256B per 16-lane group

    // right: decode segmax(raw f32 x), same monotone map
    int seg = unq[p];
    uint4 m4 = ((const uint4*)segmax)[(long)seg * 16 + qq];
    f4v z4;
    z4.x = fmaxf(fmaf(dec_f(m4.x), sc4.x, sh4.x), 0.f);
    z4.y = fmaxf(fmaf(dec_f(m4.y), sc4.y, sh4.y), 0.f);
    z4.z = fmaxf(fmaf(dec_f(m4.z), sc4.z, sh4.z), 0.f);
    z4.w = fmaxf(fmaf(dec_f(m4.w), sc4.w, sh4.w), 0.f);
    __builtin_nontemporal_store(z4, (f4v*)out + p * 32 + 16 + qq); // dense 256B per 16-lane group
}

extern "C" void kernel_launch(void* const* d_in, const int* in_sizes, int n_in,
                              void* d_out, int out_size, void* d_ws, size_t ws_size,
                              hipStream_t stream) {
    const float* in    = (const float*)d_in[0];
    const float* W     = (const float*)d_in[1];
    const float* gamma = (const float*)d_in[2];
    const float* beta  = (const float*)d_in[3];
    const void*  unq   = d_in[4];
    float* out = (float*)d_out;

    const int N   = in_sizes[0] / 64;
    const int NB  = (N + 127) / 128;
    const int NBS = 4 * NB;

    char* ws = (char*)d_ws;
    unsigned int* segmax = (unsigned int*)ws;                    // 10.24 MB (encoded floats)
    size_t off = (size_t)NUM_SEG * 64 * 4;
    float* sums = (float*)(ws + off); off += (size_t)64 * NBS * 4;
    float* sqs  = (float*)(ws + off); off += (size_t)64 * NBS * 4;
    float* ss   = (float*)(ws + off); off += 512;
    int*   unq32= (int*)(ws + off);   off += (size_t)N * 4;
    off = (off + 255) & ~(size_t)255;
    f16x8* xtmp = (f16x8*)(ws + off); off += (size_t)N * 64 * 2; // 128 MB dense f16 raw-x

    const int n4 = NUM_SEG * 64 / 4;
    const int gprep = max((N + 255) / 256, (n4 + 255) / 256);
    k_prep<<<gprep, 256, 0, stream>>>(unq, N, unq32, (float4*)segmax, n4);
    k1_mfma<<<NB, 256, 0, stream>>>(in, W, unq32, xtmp, sums, sqs, segmax, N, NBS);
    k2_stats<<<64, 256, 0, stream>>>(sums, sqs, gamma, beta, ss, N, NBS);
    k4_final<<<(int)(((long)N * 16 + 255) / 256), 256, 0, stream>>>(out, unq32, (const f16x4v*)xtmp, segmax, ss, N);
}

// Round 22
// 237.117 us; speedup vs baseline: 1.8135x; 1.0745x over previous
//
#include <hip/hip_runtime.h>

#define NUM_SEG 40000
#define BN_EPS 1e-3f

typedef float f4v __attribute__((ext_vector_type(4)));
typedef _Float16 f16x8 __attribute__((ext_vector_type(8)));
typedef _Float16 f16x4v __attribute__((ext_vector_type(4)));
typedef float f32x4 __attribute__((ext_vector_type(4)));

// Order-preserving float->uint encoding (for atomicMax over signed floats).
__device__ __forceinline__ unsigned enc_f(float f) {
    unsigned b = __float_as_uint(f);
    return (b & 0x80000000u) ? ~b : (b | 0x80000000u);
}
__device__ __forceinline__ float dec_f(unsigned u) {
    return __uint_as_float((u & 0x80000000u) ? (u ^ 0x80000000u) : ~u);
}

// Direct global->LDS DMA, 16B per lane. LDS dest is WAVE-UNIFORM base (HW adds lane*16);
// global src is per-lane (pre-swizzled to realize the LDS swizzle — m173 pattern).
// aux=2 -> CPol NT (gfx94x): 'in' is read-once; don't let it evict xtmp from L3.
__device__ __forceinline__ void gload_lds16_nt(const void* g, void* l) {
    __builtin_amdgcn_global_load_lds(
        (const __attribute__((address_space(1))) unsigned int*)g,
        (__attribute__((address_space(3))) unsigned int*)l, 16, 0, 2);
}

// ---------------- k_prep: zero segmax + detect int64/int32 + convert unq -> int32 ----------------
__global__ __launch_bounds__(256) void k_prep(const void* __restrict__ unq, int N,
                                              int* __restrict__ unq32,
                                              float4* __restrict__ segz, int nseg4) {
    __shared__ int sflag;
    const int tid = threadIdx.x;
    if (tid < 64) {
        const unsigned int* u = (const unsigned int*)unq;
        int w = ((N / 2) | 1) + 2 * tid;
        unsigned v = (w < N) ? u[w] : 0u;
        unsigned long long b = __ballot(v != 0u);
        if (tid == 0) sflag = (b == 0ull) ? 1 : 0;
    }
    __syncthreads();
    const int flag = sflag;
    const long i = (long)blockIdx.x * 256 + tid;
    if (i < nseg4) segz[i] = make_float4(0.f, 0.f, 0.f, 0.f);   // 0 == enc(-inf)
    if (i < N) unq32[i] = flag ? (int)((const long long*)unq)[i] : ((const int*)unq)[i];
}

// ---------------- k1: f16 2-term MFMA matmul -> raw x to DENSE f16 xtmp, stats, segmax over RAW x ----------------
// LDS 40KB: A_f32[128][256B] chunk-swizzled (c^=(r&15)) at 0; W16_t[64][128B] (c^=(n&7)) at 32768.
// 4 blocks/CU * 4 waves = 16 waves/CU. x = ahi@W16 + alo@W16 (A-split exact; W f16 err ~2^-11).
// A staged via global_load_lds NT (read-once; preserve L3 for xtmp, which k4 re-reads).
__global__ __launch_bounds__(256, 4) void k1_mfma(
    const float* __restrict__ in, const float* __restrict__ W,
    const int* __restrict__ unq,
    f16x8* __restrict__ xtmp, float* __restrict__ sums, float* __restrict__ sqs,
    unsigned int* __restrict__ segmax, int N, int NBS) {
    __shared__ __align__(16) char lds[40960];
    // overlay after barrier: xbuf = (float*)lds, [128][68] f32 (34.8KB <= 40KB)
    const int tid = threadIdx.x;
    const int blk = blockIdx.x;
    const long p0 = (long)blk * 128;
    const int wv = tid >> 6;
    const int l  = tid & 63;

    // --- stage W16_t: wave wv covers k in [wv*16, +16); lane l = out-ch n ---
    {
        _Float16 h[16];
        #pragma unroll
        for (int kk = 0; kk < 16; ++kk)
            h[kk] = (_Float16)W[(wv * 16 + kk) * 64 + l];   // coalesced 256B row per kk
        f16x8 c0 = { h[0], h[1], h[2], h[3], h[4], h[5], h[6], h[7] };
        f16x8 c1 = { h[8], h[9], h[10], h[11], h[12], h[13], h[14], h[15] };
        int base = 32768 + l * 128;
        *(f16x8*)(lds + base + (((wv * 2)     ^ (l & 7)) << 4)) = c0;
        *(f16x8*)(lds + base + (((wv * 2 + 1) ^ (l & 7)) << 4)) = c1;
    }
    // --- stage A: 2048 16B chunks; fast path = direct global->LDS DMA (NT), pre-swizzled source ---
    if (p0 + 128 <= (long)N) {
        #pragma unroll
        for (int it = 0; it < 8; ++it) {
            int w = it * 4 + wv;                 // 1KB window index (wave-uniform)
            int q = w * 64 + l;                  // chunk this lane fetches
            int r = q >> 4, c = q & 15;
            gload_lds16_nt((const f4v*)in + (p0 + r) * 16 + (c ^ (r & 15)),
                           lds + w * 1024);
        }
    } else {
        #pragma unroll
        for (int it = 0; it < 8; ++it) {         // tail block: guarded VGPR path
            int f = it * 256 + tid;
            int r = f >> 4, c = f & 15;
            long gp = p0 + r;
            f4v v = {0.f, 0.f, 0.f, 0.f};
            if (gp < N) v = *((const f4v*)in + gp * 16 + c);
            *(f4v*)(lds + r * 256 + ((c ^ (r & 15)) << 4)) = v;
        }
    }
    __syncthreads();

    // --- MFMA: wave wv owns rows [wv*32, +32), all 64 channels ---
    const int lr = l & 15;
    const int lg = l >> 4;
    f32x4 acc[2][4] = {};
    #pragma unroll
    for (int ks = 0; ks < 2; ++ks) {
        f16x8 ah[2], al[2], bh[4];
        #pragma unroll
        for (int mt = 0; mt < 2; ++mt) {
            int r = wv * 32 + mt * 16 + lr;
            int cg = ks * 8 + lg * 2;                       // 16B f32 chunk index
            f4v a0 = *(const f4v*)(lds + r * 256 + (((cg)     ^ (r & 15)) << 4));
            f4v a1 = *(const f4v*)(lds + r * 256 + (((cg + 1) ^ (r & 15)) << 4));
            float av[8] = { a0.x, a0.y, a0.z, a0.w, a1.x, a1.y, a1.z, a1.w };
            #pragma unroll
            for (int j = 0; j < 8; ++j) {
                _Float16 h = (_Float16)av[j];
                ah[mt][j] = h;
                al[mt][j] = (_Float16)(av[j] - (float)h);
            }
        }
        #pragma unroll
        for (int nt = 0; nt < 4; ++nt) {
            int n = nt * 16 + lr;
            int cg = ks * 4 + lg;                           // 16B f16 chunk index
            bh[nt] = *(const f16x8*)(lds + 32768 + n * 128 + ((cg ^ (n & 7)) << 4));
        }
        #pragma unroll
        for (int mt = 0; mt < 2; ++mt)
            #pragma unroll
            for (int nt = 0; nt < 4; ++nt) {
                acc[mt][nt] = __builtin_amdgcn_mfma_f32_16x16x32_f16(ah[mt], bh[nt], acc[mt][nt], 0, 0, 0);
                acc[mt][nt] = __builtin_amdgcn_mfma_f32_16x16x32_f16(al[mt], bh[nt], acc[mt][nt], 0, 0, 0);
            }
    }

    // --- stats: channel c = nt*16 + lr; sum over this wave's 32 points ---
    {
        float s[4], q[4];
        #pragma unroll
        for (int nt = 0; nt < 4; ++nt) {
            s[nt] = 0.f; q[nt] = 0.f;
            #pragma unroll
            for (int mt = 0; mt < 2; ++mt)
                #pragma unroll
                for (int r = 0; r < 4; ++r) {
                    float x = acc[mt][nt][r];
                    s[nt] += x; q[nt] += x * x;
                }
        }
        #pragma unroll
        for (int off = 16; off < 64; off <<= 1) {   // sum lanes sharing lr
            #pragma unroll
            for (int nt = 0; nt < 4; ++nt) {
                s[nt] += __shfl_xor(s[nt], off);
                q[nt] += __shfl_xor(q[nt], off);
            }
        }
        if (l < 16) {
            #pragma unroll
            for (int nt = 0; nt < 4; ++nt) {
                int c = nt * 16 + l;
                sums[(long)c * NBS + blk * 4 + wv] = s[nt];
                sqs [(long)c * NBS + blk * 4 + wv] = q[nt];
            }
        }
    }

    // --- restage raw x into xbuf (overlays staging tiles) ---
    __syncthreads();   // all frag reads done
    float* xbuf = (float*)lds;
    #pragma unroll
    for (int mt = 0; mt < 2; ++mt)
        #pragma unroll
        for (int nt = 0; nt < 4; ++nt)
            #pragma unroll
            for (int r = 0; r < 4; ++r)
                xbuf[(wv * 32 + mt * 16 + lg * 4 + r) * 68 + nt * 16 + lr] = acc[mt][nt][r];
    __syncthreads();

    // --- DENSE store raw x as f16 -> xtmp (128B/point; 1KB contiguous per wave; cacheable for k4) ---
    #pragma unroll
    for (int it = 0; it < 4; ++it) {
        int f = it * 256 + tid;
        int p = f >> 3, c = f & 7;
        long gp = p0 + p;
        if (gp < N) {
            const float* src = &xbuf[p * 68 + c * 8];
            f16x8 h;
            #pragma unroll
            for (int j = 0; j < 8; ++j) h[j] = (_Float16)src[j];
            xtmp[gp * 8 + c] = h;
        }
    }

    // --- per-wave run-compressed segmax over raw x: 32 consecutive points, lane = channel ---
    const long gbase = p0 + (long)wv * 32;
    if (gbase < N) {
        const int cnt = (int)min((long)32, (long)N - gbase);
        const int myseg = unq[gbase + ((l < cnt) ? l : (cnt - 1))];
        int cur = __shfl(myseg, 0);
        unsigned runmax = 0u;
        for (int r = 0; r < cnt; ++r) {
            int seg = __shfl(myseg, r);
            if (seg != cur) {
                atomicMax(&segmax[(long)cur * 64 + l], runmax);
                cur = seg; runmax = 0u;
            }
            runmax = max(runmax, enc_f(xbuf[(wv * 32 + r) * 68 + l]));
        }
        atomicMax(&segmax[(long)cur * 64 + l], runmax);
    }
}

// ---------------- k2: reduce partials -> scale/shift per channel ----------------
__global__ __launch_bounds__(256) void k2_stats(
    const float* __restrict__ sums, const float* __restrict__ sqs,
    const float* __restrict__ gamma, const float* __restrict__ beta,
    float* __restrict__ ss, int N, int NBS) {
    int c = blockIdx.x;
    int tid = threadIdx.x;
    float s = 0.f, q = 0.f;
    for (int i = tid; i < NBS; i += 256) { s += sums[(long)c * NBS + i]; q += sqs[(long)c * NBS + i]; }
    __shared__ float ls[256], lq[256];
    ls[tid] = s; lq[tid] = q;
    __syncthreads();
    for (int off = 128; off > 0; off >>= 1) {
        if (tid < off) { ls[tid] += ls[tid + off]; lq[tid] += lq[tid + off]; }
        __syncthreads();
    }
    if (tid == 0) {
        float mean = ls[0] / (float)N;
        float var  = lq[0] / (float)N - mean * mean;   // biased, matches jnp.var
        float sc = gamma[c] * rsqrtf(var + BN_EPS);
        float sh = beta[c] - mean * sc;
        ss[c] = sc; ss[64 + c] = sh;
    }
}

// ---------------- k4: 16 thr/point, qq owns left-f4 qq AND right-f4 qq (dense 256B runs) ----------------
__global__ __launch_bounds__(256) void k4_final(
    float* __restrict__ out, const int* __restrict__ unq,
    const f16x4v* __restrict__ xtmp,
    const unsigned int* __restrict__ segmax, const float* __restrict__ ss, int N) {
    long t = (long)blockIdx.x * 256 + threadIdx.x;
    long p = t >> 4;
    int qq = (int)(t & 15);
    if (p >= N) return;
    const float4* ss4 = (const float4*)ss;
    float4 sc4 = ss4[qq], sh4 = ss4[16 + qq];

    // left: y = relu(sc*x + sh); x from f16 xtmp (8B/lane, 128B contiguous per point)
    f16x4v h = xtmp[p * 16 + qq];
    f4v y4;
    y4.x = fmaxf(fmaf((float)h[0], sc4.x, sh4.x), 0.f);
    y4.y = fmaxf(fmaf((float)h[1], sc4.y, sh4.y), 0.f);
    y4.z = fmaxf(fmaf((float)h[2], sc4.z, sh4.z), 0.f);
    y4.w = fmaxf(fmaf((float)h[3], sc4.w, sh4.w), 0.f);
    __builtin_nontemporal_store(y4, (f4v*)out + p * 32 + qq);      // dense 256B per 16-lane group

    // right: decode segmax(raw f32 x), same monotone map
    int seg = unq[p];
    uint4 m4 = ((const uint4*)segmax)[(long)seg * 16 + qq];
    f4v z4;
    z4.x = fmaxf(fmaf(dec_f(m4.x), sc4.x, sh4.x), 0.f);
    z4.y = fmaxf(fmaf(dec_f(m4.y), sc4.y, sh4.y), 0.f);
    z4.z = fmaxf(fmaf(dec_f(m4.z), sc4.z, sh4.z), 0.f);
    z4.w = fmaxf(fmaf(dec_f(m4.w), sc4.w, sh4.w), 0.f);
    __builtin_nontemporal_store(z4, (f4v*)out + p * 32 + 16 + qq); // dense 256B per 16-lane group
}

extern "C" void kernel_launch(void* const* d_in, const int* in_sizes, int n_in,
                              void* d_out, int out_size, void* d_ws, size_t ws_size,
                              hipStream_t stream) {
    const float* in    = (const float*)d_in[0];
    const float* W     = (const float*)d_in[1];
    const float* gamma = (const float*)d_in[2];
    const float* beta  = (const float*)d_in[3];
    const void*  unq   = d_in[4];
    float* out = (float*)d_out;

    const int N   = in_sizes[0] / 64;
    const int NB  = (N + 127) / 128;
    const int NBS = 4 * NB;

    char* ws = (char*)d_ws;
    unsigned int* segmax = (unsigned int*)ws;                    // 10.24 MB (encoded floats)
    size_t off = (size_t)NUM_SEG * 64 * 4;
    float* sums = (float*)(ws + off); off += (size_t)64 * NBS * 4;
    float* sqs  = (float*)(ws + off); off += (size_t)64 * NBS * 4;
    float* ss   = (float*)(ws + off); off += 512;
    int*   unq32= (int*)(ws + off);   off += (size_t)N * 4;
    off = (off + 255) & ~(size_t)255;
    f16x8* xtmp = (f16x8*)(ws + off); off += (size_t)N * 64 * 2; // 128 MB dense f16 raw-x

    const int n4 = NUM_SEG * 64 / 4;
    const int gprep = max((N + 255) / 256, (n4 + 255) / 256);
    k_prep<<<gprep, 256, 0, stream>>>(unq, N, unq32, (float4*)segmax, n4);
    k1_mfma<<<NB, 256, 0, stream>>>(in, W, unq32, xtmp, sums, sqs, segmax, N, NBS);
    k2_stats<<<64, 256, 0, stream>>>(sums, sqs, gamma, beta, ss, N, NBS);
    k4_final<<<(int)(((long)N * 16 + 255) / 256), 256, 0, stream>>>(out, unq32, (const f16x4v*)xtmp, segmax, ss, N);
}